// Round 1
// baseline (106.138 us; speedup 1.0000x reference)
//
#include <hip/hip_runtime.h>
#include <hip/hip_bf16.h>

// 2:4 structured pruning: for each contiguous block of 4 floats (row-major),
// keep the 2 largest-|x| (ties -> lower index wins, matching jax.lax.top_k),
// zero the other 2. update_mask/apply_mask are runtime scalars (both 1 in the
// harness); if either is 0 the op degenerates to a copy.

__global__ __launch_bounds__(256) void Sparsity_48009144435553_kernel(
    const float4* __restrict__ in, float4* __restrict__ out,
    const int* __restrict__ um, const int* __restrict__ am,
    long long nblk) {
    const bool prune = (um[0] != 0) && (am[0] != 0);
    const long long stride = (long long)gridDim.x * blockDim.x;
    for (long long i = (long long)blockIdx.x * blockDim.x + threadIdx.x;
         i < nblk; i += stride) {
        float4 v = in[i];
        if (prune) {
            const float a0 = fabsf(v.x), a1 = fabsf(v.y),
                        a2 = fabsf(v.z), a3 = fabsf(v.w);
            // rank_i = number of j that beat i; j beats i if a_j > a_i, or
            // a_j == a_i with j < i (lower index wins ties, like top_k).
            const int r0 = (a1 > a0) + (a2 > a0) + (a3 > a0);
            const int r1 = (a0 >= a1) + (a2 > a1) + (a3 > a1);
            const int r2 = (a0 >= a2) + (a1 >= a2) + (a3 > a2);
            const int r3 = (a0 >= a3) + (a1 >= a3) + (a2 >= a3);
            v.x = (r0 < 2) ? v.x : 0.0f;
            v.y = (r1 < 2) ? v.y : 0.0f;
            v.z = (r2 < 2) ? v.z : 0.0f;
            v.w = (r3 < 2) ? v.w : 0.0f;
        }
        out[i] = v;
    }
}

extern "C" void kernel_launch(void* const* d_in, const int* in_sizes, int n_in,
                              void* d_out, int out_size, void* d_ws, size_t ws_size,
                              hipStream_t stream) {
    const float4* in = (const float4*)d_in[0];
    const int* um = (const int*)d_in[1];
    const int* am = (const int*)d_in[2];
    float4* out = (float4*)d_out;

    const long long nblk = (long long)in_sizes[0] / 4;  // 16M float4 blocks
    const int block = 256;
    // memory-bound: cap grid at 256 CU x 8 blocks/CU, grid-stride the rest
    long long want = (nblk + block - 1) / block;
    int grid = (int)((want < 2048) ? want : 2048);

    Sparsity_48009144435553_kernel<<<grid, block, 0, stream>>>(in, out, um, am, nblk);
}